// Round 19
// baseline (527.237 us; speedup 1.0000x reference)
//
#include <hip/hip_runtime.h>
#include <hip/hip_bf16.h>

#define N_NODES 50000
#define N_EDGES 800000
#define E_TOT   (N_EDGES + N_NODES)   // 850000 with self-loops
#define IN_CH   128
#define HID     64
#define HEADS   4
#define OUT_CH  40
#define LAYERS  4
#define LN_EPS  1e-5f

#define AG_STRIDE  262   // bf16 units (R5/R8/R9/R13-proven)
#define WC_STRIDE  68    // fp32 units (R9/R13-proven)
#define NTILES    ((N_NODES + 31) / 32)   // 1563
#define PBLOCKS   1536                    // 6 blocks/CU x 256 CUs (persistent)

__device__ __forceinline__ unsigned short f2bf(float f) {
    unsigned u = __float_as_uint(f);
    unsigned r = (u + 0x7fffu + ((u >> 16) & 1u)) >> 16;   // RNE
    return (unsigned short)r;
}
__device__ __forceinline__ float bf_lo(unsigned u) { return __uint_as_float(u << 16); }
__device__ __forceinline__ float bf_hi(unsigned u) { return __uint_as_float(u & 0xffff0000u); }
__device__ __forceinline__ float lrelu(float x) { return x > 0.f ? x : 0.2f * x; }

// order-preserving float<->uint encoding for atomicMax on floats
__device__ __forceinline__ unsigned fenc(float f) {
    unsigned u = __float_as_uint(f);
    return (u & 0x80000000u) ? ~u : (u | 0x80000000u);
}
__device__ __forceinline__ float fdec(unsigned k) {
    unsigned u = (k & 0x80000000u) ? (k & 0x7fffffffu) : ~k;
    return __uint_as_float(u);
}

// ---------------- CSR build (R12-proven: rank recorded in hist, scatter has no atomics) ----------------

__global__ void k_hist(const int* __restrict__ ei, int* __restrict__ cnt,
                       int* __restrict__ rank) {
    int e = blockIdx.x * blockDim.x + threadIdx.x;
    if (e >= E_TOT) return;
    int dst = (e < N_EDGES) ? ei[N_EDGES + e] : (e - N_EDGES);
    rank[e] = atomicAdd(&cnt[dst], 1);
}

__global__ __launch_bounds__(1024) void k_scan_a(const int* __restrict__ cnt,
                                                 int* __restrict__ row_ptr,
                                                 int* __restrict__ bsum) {
    __shared__ int wt[16];
    int tid = threadIdx.x, lane = tid & 63, w = tid >> 6;
    int i = blockIdx.x * 1024 + tid;
    int v = (i < N_NODES) ? cnt[i] : 0;
    int x = v;
    for (int off = 1; off < 64; off <<= 1) {
        int t = __shfl_up(x, off, 64);
        if (lane >= off) x += t;
    }
    if (lane == 63) wt[w] = x;
    __syncthreads();
    if (w == 0) {
        int t = (lane < 16) ? wt[lane] : 0;
        for (int off = 1; off < 16; off <<= 1) {
            int u = __shfl_up(t, off, 64);
            if (lane >= off) t += u;
        }
        if (lane < 16) wt[lane] = t;
    }
    __syncthreads();
    int woff = (w > 0) ? wt[w - 1] : 0;
    if (i < N_NODES) row_ptr[i] = woff + x - v;
    if (tid == 0) bsum[blockIdx.x] = wt[15];
}

#define SCAN_BLOCKS 49   // ceil(50000/1024)

__global__ __launch_bounds__(64) void k_scan_b(const int* __restrict__ bsum,
                                               int* __restrict__ boff,
                                               int* __restrict__ row_ptr) {
    int lane = threadIdx.x;
    int v = (lane < SCAN_BLOCKS) ? bsum[lane] : 0;
    int x = v;
    for (int off = 1; off < 64; off <<= 1) {
        int t = __shfl_up(x, off, 64);
        if (lane >= off) x += t;
    }
    if (lane < SCAN_BLOCKS) boff[lane] = x - v;
    if (lane == 63) row_ptr[N_NODES] = x;
}

__global__ __launch_bounds__(256) void k_scan_c(int* __restrict__ row_ptr,
                                                const int* __restrict__ boff) {
    int i = blockIdx.x * 256 + threadIdx.x;
    if (i >= N_NODES) return;
    row_ptr[i] += boff[i >> 10];
}

__global__ void k_scatter(const int* __restrict__ ei,
                          const int* __restrict__ row_ptr,
                          const int* __restrict__ rank,
                          int* __restrict__ csr_src) {
    int e = blockIdx.x * blockDim.x + threadIdx.x;
    if (e >= E_TOT) return;
    int src, dst;
    if (e < N_EDGES) { src = ei[e]; dst = ei[N_EDGES + e]; }
    else             { src = dst = e - N_EDGES; }
    int pos = row_ptr[dst] + rank[e];
    csr_src[pos] = src;
}

// ---------------- prep: watt[l][v][64] = W_headT @ att vec ; wstack[l][256][64] fp32 ----------------

__global__ __launch_bounds__(256) void k_prep(const float* __restrict__ lin_W,
                                              const float* __restrict__ att_src,
                                              const float* __restrict__ att_dst,
                                              float* __restrict__ watt,
                                              float* __restrict__ wstack) {
    int l = blockIdx.x, tid = threadIdx.x;
    const float* Wl = lin_W + (size_t)l * HID * 256;
    {
        int k = tid, h = k >> 6, i = k & 63;
        const float* src = Wl + i * 256 + h * 64;
        float* dstp = wstack + (size_t)l * 256 * 64 + k * 64;
        for (int c = 0; c < 64; c += 4)
            *(float4*)(dstp + c) = *(const float4*)(src + c);
    }
    for (int idx = tid; idx < 512; idx += 256) {
        int v = idx >> 6, i = idx & 63;
        int h = v & 3;
        const float* av = (v < 4 ? att_src : att_dst) + (size_t)l * 256 + h * 64;
        const float* wr = Wl + i * 256 + h * 64;
        float p = 0.f;
        for (int c = 0; c < 64; ++c) p = fmaf(wr[c], av[c], p);
        watt[(size_t)l * 512 + v * 64 + i] = p;
    }
}

// ---------------- layer-0 GEMM (fp32, verified): h = elu(x @ Wi + bi) + fused layer-0 alpha ----

__global__ __launch_bounds__(256) void k_gemm_in(const float* __restrict__ x,
                                                 const float* __restrict__ Wi,
                                                 const float* __restrict__ bi,
                                                 const float* __restrict__ watt,  // [8][64]
                                                 float* __restrict__ h,
                                                 unsigned short* __restrict__ h_bf,
                                                 float* __restrict__ alpha_s,
                                                 float* __restrict__ alpha_d,
                                                 unsigned* __restrict__ mxk) {
    __shared__ float xT[IN_CH * 64];
    __shared__ float Ws[IN_CH * HID];
    __shared__ float wl[512];
    __shared__ unsigned s_mx[4];
    int tid = threadIdx.x;
    int row0 = blockIdx.x * 64;
    if (tid < 4) s_mx[tid] = 0;
    for (int i = tid; i < 512; i += 256) wl[i] = watt[i];
    for (int i = tid * 4; i < IN_CH * HID; i += 1024)
        *(float4*)(Ws + i) = *(const float4*)(Wi + i);
    {
        int r = tid >> 2, k0 = (tid & 3) * 32;
        int rr = row0 + r;
#pragma unroll
        for (int j = 0; j < 32; j += 4) {
            float4 v = (rr < N_NODES) ? *(const float4*)(x + (size_t)rr * IN_CH + k0 + j)
                                      : make_float4(0.f, 0.f, 0.f, 0.f);
            xT[(k0 + j    ) * 64 + r] = v.x;
            xT[(k0 + j + 1) * 64 + r] = v.y;
            xT[(k0 + j + 2) * 64 + r] = v.z;
            xT[(k0 + j + 3) * 64 + r] = v.w;
        }
    }
    __syncthreads();
    int tx = tid & 15, ty = tid >> 4;
    int c0 = tx * 4, r0 = ty * 4;
    float acc[4][4] = {};
    for (int k = 0; k < IN_CH; ++k) {
        float4 xv = *(const float4*)(xT + k * 64 + r0);
        float4 wv = *(const float4*)(Ws + k * HID + c0);
        float xr[4] = {xv.x, xv.y, xv.z, xv.w};
        float wc[4] = {wv.x, wv.y, wv.z, wv.w};
#pragma unroll
        for (int r = 0; r < 4; ++r)
#pragma unroll
            for (int c = 0; c < 4; ++c)
                acc[r][c] = fmaf(xr[r], wc[c], acc[r][c]);
    }
    float4 bv = *(const float4*)(bi + c0);
    float bcs[4] = {bv.x, bv.y, bv.z, bv.w};
    float rpmax[4] = {-1e30f, -1e30f, -1e30f, -1e30f};
#pragma unroll
    for (int r = 0; r < 4; ++r) {
        int rr = row0 + r0 + r;
        float vv[4];
#pragma unroll
        for (int c = 0; c < 4; ++c) {
            float t = acc[r][c] + bcs[c];
            vv[c] = t > 0.f ? t : (__expf(t) - 1.f);
        }
        if (rr < N_NODES) {
            *(float4*)(h + (size_t)rr * HID + c0) = make_float4(vv[0], vv[1], vv[2], vv[3]);
            unsigned short t4[4] = {f2bf(vv[0]), f2bf(vv[1]), f2bf(vv[2]), f2bf(vv[3])};
            *(uint2*)(h_bf + (size_t)rr * HID + c0) = *(uint2*)t4;
        }
        float red[8];
#pragma unroll
        for (int v = 0; v < 8; ++v) {
            const float* wv = wl + v * 64 + c0;
            float p = vv[0]*wv[0] + vv[1]*wv[1] + vv[2]*wv[2] + vv[3]*wv[3];
            p += __shfl_xor(p, 1, 64);
            p += __shfl_xor(p, 2, 64);
            p += __shfl_xor(p, 4, 64);
            p += __shfl_xor(p, 8, 64);
            red[v] = p;
        }
        if (tx == 0 && rr < N_NODES) {
            *(float4*)(alpha_s + (size_t)rr * 4) = make_float4(red[0], red[1], red[2], red[3]);
            *(float4*)(alpha_d + (size_t)rr * 4) = make_float4(red[4], red[5], red[6], red[7]);
#pragma unroll
            for (int hh = 0; hh < 4; ++hh) rpmax[hh] = fmaxf(rpmax[hh], red[hh]);
        }
    }
    if (tx == 0) {
#pragma unroll
        for (int hh = 0; hh < 4; ++hh) atomicMax(&s_mx[hh], fenc(rpmax[hh]));
    }
    __syncthreads();
    if (tid < 4) atomicMax(&mxk[tid], s_mx[tid]);
}

// ---------------- fused layer (persistent blocks, dynamic 32-node tiles) ----------------
// Phase 1: 8 lanes/node, depth-1 pipelined gathers (R15-proven). Phase 2 = R13 post GEMV.
// Tiles grabbed via global atomic counter -> eliminates the static-assignment ramp-down tail.
// Per-tile code identical to R18 -> bit-identical numerics.

__global__ __launch_bounds__(256) void k_layer(
    const unsigned short* __restrict__ h_bf,    // [N][64] bf16 (current layer)
    const float* __restrict__ alpha_s,          // current
    const float* __restrict__ alpha_d,          // current
    const int* __restrict__ row_ptr,
    const int* __restrict__ csr_src,
    const unsigned* __restrict__ mxk,           // current [4]
    const float* __restrict__ wstack,           // [256][64] fp32
    const float* __restrict__ gat_b,
    const float* __restrict__ ln_g,
    const float* __restrict__ ln_b,
    const float* __restrict__ h_res,            // fp32 h (current layer input)
    const float* __restrict__ watt_next,        // [8][64]
    float* __restrict__ h_out,                  // fp32 next
    unsigned short* __restrict__ hbf_out,       // bf16 next (other buffer!)
    float* __restrict__ alpha_s_nxt,
    float* __restrict__ alpha_d_nxt,
    unsigned* __restrict__ mxk_next,
    int* __restrict__ tile_counter,
    int use_res, int do_alpha)
{
    __shared__ unsigned short aS[32 * AG_STRIDE];   // 16768 B
    __shared__ float Wc[32 * WC_STRIDE];            // 8704 B
    __shared__ unsigned s_mx[4];
    __shared__ int s_tile;
    int tid = threadIdx.x;

    for (;;) {
        if (tid == 0) s_tile = atomicAdd(tile_counter, 1);
        if (tid < 4) s_mx[tid] = 0;
        __syncthreads();           // publishes s_tile + s_mx; fences aS reuse from prev tile
        int tile = s_tile;
        if (tile >= NTILES) break; // uniform exit
        int row0 = tile * 32;

        // -------- phase 1: aggregate this tile's 32 nodes into aS (pipelined gathers) --------
        {
            int dl = tid >> 3, q = tid & 7;
            int d = row0 + dl;
            unsigned short* arow = aS + dl * AG_STRIDE + (q << 3);
            if (d < N_NODES) {
                int start = row_ptr[d], end = row_ptr[d + 1];
                float4 ad = *(const float4*)(alpha_d + (size_t)d * 4);
                float mp0 = lrelu(fdec(mxk[0]) + ad.x);
                float mp1 = lrelu(fdec(mxk[1]) + ad.y);
                float mp2 = lrelu(fdec(mxk[2]) + ad.z);
                float mp3 = lrelu(fdec(mxk[3]) + ad.w);

                float acc[4][8] = {};
                float ds0 = 0.f, ds1 = 0.f, ds2 = 0.f, ds3 = 0.f;

                int s = csr_src[start];
                float4 as = *(const float4*)(alpha_s + (size_t)s * 4);
                uint4  u  = *(const uint4*)(h_bf + ((size_t)s << 6) + (q << 3));

                for (int e = start; e < end; ++e) {
                    int sn = (e + 1 < end) ? csr_src[e + 1] : 0;
                    float4 as_n = *(const float4*)(alpha_s + (size_t)sn * 4);
                    uint4  u_n  = *(const uint4*)(h_bf + ((size_t)sn << 6) + (q << 3));

                    float w0 = __expf(lrelu(as.x + ad.x) - mp0);
                    float w1 = __expf(lrelu(as.y + ad.y) - mp1);
                    float w2 = __expf(lrelu(as.z + ad.z) - mp2);
                    float w3 = __expf(lrelu(as.w + ad.w) - mp3);
                    ds0 += w0; ds1 += w1; ds2 += w2; ds3 += w3;
                    float f0 = bf_lo(u.x), f1 = bf_hi(u.x), f2 = bf_lo(u.y), f3 = bf_hi(u.y);
                    float f4 = bf_lo(u.z), f5 = bf_hi(u.z), f6 = bf_lo(u.w), f7 = bf_hi(u.w);
                    acc[0][0] = fmaf(w0, f0, acc[0][0]); acc[0][1] = fmaf(w0, f1, acc[0][1]);
                    acc[0][2] = fmaf(w0, f2, acc[0][2]); acc[0][3] = fmaf(w0, f3, acc[0][3]);
                    acc[0][4] = fmaf(w0, f4, acc[0][4]); acc[0][5] = fmaf(w0, f5, acc[0][5]);
                    acc[0][6] = fmaf(w0, f6, acc[0][6]); acc[0][7] = fmaf(w0, f7, acc[0][7]);
                    acc[1][0] = fmaf(w1, f0, acc[1][0]); acc[1][1] = fmaf(w1, f1, acc[1][1]);
                    acc[1][2] = fmaf(w1, f2, acc[1][2]); acc[1][3] = fmaf(w1, f3, acc[1][3]);
                    acc[1][4] = fmaf(w1, f4, acc[1][4]); acc[1][5] = fmaf(w1, f5, acc[1][5]);
                    acc[1][6] = fmaf(w1, f6, acc[1][6]); acc[1][7] = fmaf(w1, f7, acc[1][7]);
                    acc[2][0] = fmaf(w2, f0, acc[2][0]); acc[2][1] = fmaf(w2, f1, acc[2][1]);
                    acc[2][2] = fmaf(w2, f2, acc[2][2]); acc[2][3] = fmaf(w2, f3, acc[2][3]);
                    acc[2][4] = fmaf(w2, f4, acc[2][4]); acc[2][5] = fmaf(w2, f5, acc[2][5]);
                    acc[2][6] = fmaf(w2, f6, acc[2][6]); acc[2][7] = fmaf(w2, f7, acc[2][7]);
                    acc[3][0] = fmaf(w3, f0, acc[3][0]); acc[3][1] = fmaf(w3, f1, acc[3][1]);
                    acc[3][2] = fmaf(w3, f2, acc[3][2]); acc[3][3] = fmaf(w3, f3, acc[3][3]);
                    acc[3][4] = fmaf(w3, f4, acc[3][4]); acc[3][5] = fmaf(w3, f5, acc[3][5]);
                    acc[3][6] = fmaf(w3, f6, acc[3][6]); acc[3][7] = fmaf(w3, f7, acc[3][7]);

                    as = as_n; u = u_n; s = sn;
                }

                float inv[4] = {1.f / (ds0 + 1e-16f), 1.f / (ds1 + 1e-16f),
                                1.f / (ds2 + 1e-16f), 1.f / (ds3 + 1e-16f)};
#pragma unroll
                for (int hh = 0; hh < 4; ++hh) {
                    unsigned short t8[8];
#pragma unroll
                    for (int k = 0; k < 8; ++k) t8[k] = f2bf(acc[hh][k] * inv[hh]);
                    *(uint4*)(arow + hh * 64) = *(uint4*)t8;
                }
            } else {
                uint4 z = make_uint4(0, 0, 0, 0);
#pragma unroll
                for (int hh = 0; hh < 4; ++hh) *(uint4*)(arow + hh * 64) = z;
            }
        }

        // -------- phase 2: y = aS @ W * 0.25 + bias; LN; ELU; residual; next alpha --------
        int tx = tid & 15, ty = tid >> 4;
        int c0 = tx * 4, r0 = ty * 2;
        float acc[2][4] = {};

        int wk = tid >> 3;            // 0..31 : k-row within chunk this thread stages
        int wc8 = (tid & 7) * 8;      // 8-col group
        for (int chunk = 0; chunk < 8; ++chunk) {
            __syncthreads();   // first iteration: covers aS readiness; later: Wc reader/writer fence
            {
                const float* wsrc = wstack + (size_t)(chunk * 32 + wk) * 64 + wc8;
                float* wdst = Wc + wk * WC_STRIDE + wc8;
                *(float4*)(wdst)     = *(const float4*)(wsrc);
                *(float4*)(wdst + 4) = *(const float4*)(wsrc + 4);
            }
            __syncthreads();
            int kbase = chunk * 32;
#pragma unroll
            for (int kb = 0; kb < 8; ++kb) {
                int kl = kb * 4;
                float4 w0 = *(const float4*)(Wc + (kl + 0) * WC_STRIDE + c0);
                float4 w1 = *(const float4*)(Wc + (kl + 1) * WC_STRIDE + c0);
                float4 w2 = *(const float4*)(Wc + (kl + 2) * WC_STRIDE + c0);
                float4 w3 = *(const float4*)(Wc + (kl + 3) * WC_STRIDE + c0);
#pragma unroll
                for (int r = 0; r < 2; ++r) {
                    uint2 au = *(const uint2*)(aS + (r0 + r) * AG_STRIDE + kbase + kl);
                    float a0 = bf_lo(au.x), a1 = bf_hi(au.x), a2 = bf_lo(au.y), a3 = bf_hi(au.y);
                    acc[r][0] = fmaf(a0, w0.x, fmaf(a1, w1.x, fmaf(a2, w2.x, fmaf(a3, w3.x, acc[r][0]))));
                    acc[r][1] = fmaf(a0, w0.y, fmaf(a1, w1.y, fmaf(a2, w2.y, fmaf(a3, w3.y, acc[r][1]))));
                    acc[r][2] = fmaf(a0, w0.z, fmaf(a1, w1.z, fmaf(a2, w2.z, fmaf(a3, w3.z, acc[r][2]))));
                    acc[r][3] = fmaf(a0, w0.w, fmaf(a1, w1.w, fmaf(a2, w2.w, fmaf(a3, w3.w, acc[r][3]))));
                }
            }
        }

        float4 gb = *(const float4*)(gat_b + c0);
        float bias[4] = {gb.x, gb.y, gb.z, gb.w};
        float4 lg = *(const float4*)(ln_g + c0);
        float4 lb = *(const float4*)(ln_b + c0);
        float gg[4] = {lg.x, lg.y, lg.z, lg.w};
        float bb[4] = {lb.x, lb.y, lb.z, lb.w};
        float rpmax[4] = {-1e30f, -1e30f, -1e30f, -1e30f};
#pragma unroll
        for (int r = 0; r < 2; ++r) {
            int rr = row0 + r0 + r;
            float o[4];
#pragma unroll
            for (int c = 0; c < 4; ++c) o[c] = acc[r][c] * 0.25f + bias[c];
            float s = o[0] + o[1] + o[2] + o[3];
            float s2 = o[0]*o[0] + o[1]*o[1] + o[2]*o[2] + o[3]*o[3];
            for (int off = 1; off < 16; off <<= 1) {
                s  += __shfl_xor(s,  off, 64);
                s2 += __shfl_xor(s2, off, 64);
            }
            float mu = s * (1.f / 64.f);
            float var = s2 * (1.f / 64.f) - mu * mu;
            float rstd = rsqrtf(var + LN_EPS);
            float vv[4];
#pragma unroll
            for (int c = 0; c < 4; ++c) {
                float t = (o[c] - mu) * rstd * gg[c] + bb[c];
                vv[c] = t > 0.f ? t : (__expf(t) - 1.f);
            }
            if (rr < N_NODES) {
                if (use_res) {
                    float4 rv = *(const float4*)(h_res + (size_t)rr * HID + c0);
                    vv[0] += rv.x; vv[1] += rv.y; vv[2] += rv.z; vv[3] += rv.w;
                }
                *(float4*)(h_out + (size_t)rr * HID + c0) = make_float4(vv[0], vv[1], vv[2], vv[3]);
                unsigned short t4[4] = {f2bf(vv[0]), f2bf(vv[1]), f2bf(vv[2]), f2bf(vv[3])};
                *(uint2*)(hbf_out + (size_t)rr * HID + c0) = *(uint2*)t4;
            }
            if (do_alpha) {
                float red[8];
#pragma unroll
                for (int v = 0; v < 8; ++v) {
                    const float* wv = watt_next + v * 64 + c0;
                    float p = vv[0]*wv[0] + vv[1]*wv[1] + vv[2]*wv[2] + vv[3]*wv[3];
                    p += __shfl_xor(p, 1, 64);
                    p += __shfl_xor(p, 2, 64);
                    p += __shfl_xor(p, 4, 64);
                    p += __shfl_xor(p, 8, 64);
                    red[v] = p;
                }
                if (tx == 0 && rr < N_NODES) {
                    *(float4*)(alpha_s_nxt + (size_t)rr * 4) = make_float4(red[0], red[1], red[2], red[3]);
                    *(float4*)(alpha_d_nxt + (size_t)rr * 4) = make_float4(red[4], red[5], red[6], red[7]);
#pragma unroll
                    for (int hh = 0; hh < 4; ++hh) rpmax[hh] = fmaxf(rpmax[hh], red[hh]);
                }
            }
        }
        if (do_alpha) {
            if (tx == 0) {
#pragma unroll
                for (int hh = 0; hh < 4; ++hh) atomicMax(&s_mx[hh], fenc(rpmax[hh]));
            }
            __syncthreads();
            if (tid < 4) atomicMax(&mxk_next[tid], s_mx[tid]);
        }
    }
}

// ---------------- final GEMM (fp32, verified): out = h @ Wo + bo ----------------

__global__ __launch_bounds__(256) void k_gemm_out(const float* __restrict__ h,
                                                  const float* __restrict__ Wo,
                                                  const float* __restrict__ bo,
                                                  float* __restrict__ out) {
    __shared__ float Ws[HID * OUT_CH];
    __shared__ float hs[6 * HID];
    int tid = threadIdx.x;
    int row0 = blockIdx.x * 6;
    for (int i = tid; i < HID * OUT_CH; i += 256) Ws[i] = Wo[i];
    for (int i = tid; i < 6 * HID; i += 256) {
        int r = row0 + (i >> 6);
        hs[i] = (r < N_NODES) ? h[(size_t)r * HID + (i & 63)] : 0.f;
    }
    __syncthreads();
    if (tid < 240) {
        int r = tid / 40, o = tid - r * 40;
        int rr = row0 + r;
        if (rr < N_NODES) {
            float acc = bo[o];
            for (int k = 0; k < HID; ++k)
                acc = fmaf(hs[r * HID + k], Ws[k * OUT_CH + o], acc);
            out[(size_t)row0 * OUT_CH + tid] = acc;
        }
    }
}

// ---------------- launch ----------------

extern "C" void kernel_launch(void* const* d_in, const int* in_sizes, int n_in,
                              void* d_out, int out_size, void* d_ws, size_t ws_size,
                              hipStream_t stream) {
    const float* x       = (const float*)d_in[0];
    const int*   ei      = (const int*)  d_in[1];
    const float* Wi      = (const float*)d_in[2];
    const float* bi      = (const float*)d_in[3];
    const float* lin_W   = (const float*)d_in[4];
    const float* att_src = (const float*)d_in[5];
    const float* att_dst = (const float*)d_in[6];
    const float* gat_b   = (const float*)d_in[7];
    const float* ln_g    = (const float*)d_in[8];
    const float* ln_b    = (const float*)d_in[9];
    const float* Wo      = (const float*)d_in[10];
    const float* bo      = (const float*)d_in[11];
    float* out = (float*)d_out;

    char* ws = (char*)d_ws;
    size_t off = 0;
    auto alloc = [&](size_t bytes) -> void* {
        void* p = ws + off;
        off += (bytes + 255) & ~(size_t)255;
        return p;
    };
    float*          h_a      = (float*)alloc((size_t)N_NODES * HID * 4);
    float*          h_b      = (float*)alloc((size_t)N_NODES * HID * 4);
    unsigned short* hbf_a    = (unsigned short*)alloc((size_t)N_NODES * HID * 2);
    unsigned short* hbf_b    = (unsigned short*)alloc((size_t)N_NODES * HID * 2);
    float*          als_a    = (float*)alloc((size_t)N_NODES * 4 * 4);
    float*          ald_a    = (float*)alloc((size_t)N_NODES * 4 * 4);
    float*          als_b    = (float*)alloc((size_t)N_NODES * 4 * 4);
    float*          ald_b    = (float*)alloc((size_t)N_NODES * 4 * 4);
    int*            cnt      = (int*)  alloc((size_t)N_NODES * 4);
    int*            row_ptr  = (int*)  alloc((size_t)(N_NODES + 1) * 4);
    int*            csr_src  = (int*)  alloc((size_t)E_TOT * 4);
    int*            rank     = (int*)  alloc((size_t)E_TOT * 4);
    unsigned*       maxkey   = (unsigned*)alloc((size_t)LAYERS * 4 * 4);
    int*            tcnt     = (int*)  alloc((size_t)LAYERS * 4);
    int*            bsum     = (int*)  alloc((size_t)SCAN_BLOCKS * 4);
    int*            boff     = (int*)  alloc((size_t)SCAN_BLOCKS * 4);
    float*          watt     = (float*)alloc((size_t)LAYERS * 8 * 64 * 4);
    float*          wstack   = (float*)alloc((size_t)LAYERS * 256 * 64 * 4);

    hipMemsetAsync(cnt, 0, (size_t)N_NODES * 4, stream);
    hipMemsetAsync(maxkey, 0, (size_t)LAYERS * 4 * 4, stream);
    hipMemsetAsync(tcnt, 0, (size_t)LAYERS * 4, stream);

    int egrid = (E_TOT + 255) / 256;
    k_hist<<<egrid, 256, 0, stream>>>(ei, cnt, rank);
    k_scan_a<<<SCAN_BLOCKS, 1024, 0, stream>>>(cnt, row_ptr, bsum);
    k_scan_b<<<1, 64, 0, stream>>>(bsum, boff, row_ptr);
    k_scan_c<<<(N_NODES + 255) / 256, 256, 0, stream>>>(row_ptr, boff);
    k_scatter<<<egrid, 256, 0, stream>>>(ei, row_ptr, rank, csr_src);

    k_prep<<<LAYERS, 256, 0, stream>>>(lin_W, att_src, att_dst, watt, wstack);

    int rtiles = (N_NODES + 63) / 64;     // 782
    k_gemm_in<<<rtiles, 256, 0, stream>>>(x, Wi, bi, watt, h_a, hbf_a,
                                          als_a, ald_a, maxkey);

    float*          h_cur   = h_a;   float*          h_nxt   = h_b;
    unsigned short* hbf_cur = hbf_a; unsigned short* hbf_nxt = hbf_b;
    float* als_cur = als_a; float* ald_cur = ald_a;
    float* als_nxt = als_b; float* ald_nxt = ald_b;
    for (int l = 0; l < LAYERS; ++l) {
        int do_alpha = (l + 1 < LAYERS) ? 1 : 0;
        k_layer<<<PBLOCKS, 256, 0, stream>>>(hbf_cur, als_cur, ald_cur, row_ptr, csr_src,
                                             maxkey + l * 4,
                                             wstack + (size_t)l * 256 * 64,
                                             gat_b + (size_t)l * HID,
                                             ln_g + (size_t)l * HID,
                                             ln_b + (size_t)l * HID,
                                             h_cur,
                                             watt + (size_t)((l + 1) % LAYERS) * 512,
                                             h_nxt, hbf_nxt,
                                             als_nxt, ald_nxt,
                                             maxkey + (size_t)((l + 1) % LAYERS) * 4,
                                             tcnt + l,
                                             l > 0 ? 1 : 0, do_alpha);
        { float* t = h_cur; h_cur = h_nxt; h_nxt = t; }
        { unsigned short* t = hbf_cur; hbf_cur = hbf_nxt; hbf_nxt = t; }
        { float* t = als_cur; als_cur = als_nxt; als_nxt = t; }
        { float* t = ald_cur; ald_cur = ald_nxt; ald_nxt = t; }
    }

    int ogrid = (N_NODES + 5) / 6;
    k_gemm_out<<<ogrid, 256, 0, stream>>>(h_cur, Wo, bo, out);
}

// Round 20
// 468.358 us; speedup vs baseline: 1.1257x; 1.1257x over previous
//
#include <hip/hip_runtime.h>
#include <hip/hip_bf16.h>

#define N_NODES 50000
#define N_EDGES 800000
#define E_TOT   (N_EDGES + N_NODES)   // 850000 with self-loops
#define IN_CH   128
#define HID     64
#define HEADS   4
#define OUT_CH  40
#define LAYERS  4
#define LN_EPS  1e-5f

#define AG_STRIDE  262   // bf16 units (R5/R8/R9/R13-proven)
#define WC_STRIDE  68    // fp32 units (R9/R13-proven)

__device__ __forceinline__ unsigned short f2bf(float f) {
    unsigned u = __float_as_uint(f);
    unsigned r = (u + 0x7fffu + ((u >> 16) & 1u)) >> 16;   // RNE
    return (unsigned short)r;
}
__device__ __forceinline__ float bf_lo(unsigned u) { return __uint_as_float(u << 16); }
__device__ __forceinline__ float bf_hi(unsigned u) { return __uint_as_float(u & 0xffff0000u); }
__device__ __forceinline__ float lrelu(float x) { return x > 0.f ? x : 0.2f * x; }

// order-preserving float<->uint encoding for atomicMax on floats
__device__ __forceinline__ unsigned fenc(float f) {
    unsigned u = __float_as_uint(f);
    return (u & 0x80000000u) ? ~u : (u | 0x80000000u);
}
__device__ __forceinline__ float fdec(unsigned k) {
    unsigned u = (k & 0x80000000u) ? (k & 0x7fffffffu) : ~k;
    return __uint_as_float(u);
}

// ---------------- CSR build (R12-proven: rank recorded in hist, scatter has no atomics) ----------------

__global__ void k_hist(const int* __restrict__ ei, int* __restrict__ cnt,
                       int* __restrict__ rank) {
    int e = blockIdx.x * blockDim.x + threadIdx.x;
    if (e >= E_TOT) return;
    int dst = (e < N_EDGES) ? ei[N_EDGES + e] : (e - N_EDGES);
    rank[e] = atomicAdd(&cnt[dst], 1);
}

__global__ __launch_bounds__(1024) void k_scan_a(const int* __restrict__ cnt,
                                                 int* __restrict__ row_ptr,
                                                 int* __restrict__ bsum) {
    __shared__ int wt[16];
    int tid = threadIdx.x, lane = tid & 63, w = tid >> 6;
    int i = blockIdx.x * 1024 + tid;
    int v = (i < N_NODES) ? cnt[i] : 0;
    int x = v;
    for (int off = 1; off < 64; off <<= 1) {
        int t = __shfl_up(x, off, 64);
        if (lane >= off) x += t;
    }
    if (lane == 63) wt[w] = x;
    __syncthreads();
    if (w == 0) {
        int t = (lane < 16) ? wt[lane] : 0;
        for (int off = 1; off < 16; off <<= 1) {
            int u = __shfl_up(t, off, 64);
            if (lane >= off) t += u;
        }
        if (lane < 16) wt[lane] = t;
    }
    __syncthreads();
    int woff = (w > 0) ? wt[w - 1] : 0;
    if (i < N_NODES) row_ptr[i] = woff + x - v;
    if (tid == 0) bsum[blockIdx.x] = wt[15];
}

#define SCAN_BLOCKS 49   // ceil(50000/1024)

__global__ __launch_bounds__(64) void k_scan_b(const int* __restrict__ bsum,
                                               int* __restrict__ boff,
                                               int* __restrict__ row_ptr) {
    int lane = threadIdx.x;
    int v = (lane < SCAN_BLOCKS) ? bsum[lane] : 0;
    int x = v;
    for (int off = 1; off < 64; off <<= 1) {
        int t = __shfl_up(x, off, 64);
        if (lane >= off) x += t;
    }
    if (lane < SCAN_BLOCKS) boff[lane] = x - v;
    if (lane == 63) row_ptr[N_NODES] = x;
}

__global__ __launch_bounds__(256) void k_scan_c(int* __restrict__ row_ptr,
                                                const int* __restrict__ boff) {
    int i = blockIdx.x * 256 + threadIdx.x;
    if (i >= N_NODES) return;
    row_ptr[i] += boff[i >> 10];
}

__global__ void k_scatter(const int* __restrict__ ei,
                          const int* __restrict__ row_ptr,
                          const int* __restrict__ rank,
                          int* __restrict__ csr_src) {
    int e = blockIdx.x * blockDim.x + threadIdx.x;
    if (e >= E_TOT) return;
    int src, dst;
    if (e < N_EDGES) { src = ei[e]; dst = ei[N_EDGES + e]; }
    else             { src = dst = e - N_EDGES; }
    int pos = row_ptr[dst] + rank[e];
    csr_src[pos] = src;
}

// ---------------- prep: watt[l][v][64] = W_headT @ att vec ; wstack[l][256][64] fp32 ----------------

__global__ __launch_bounds__(256) void k_prep(const float* __restrict__ lin_W,
                                              const float* __restrict__ att_src,
                                              const float* __restrict__ att_dst,
                                              float* __restrict__ watt,
                                              float* __restrict__ wstack) {
    int l = blockIdx.x, tid = threadIdx.x;
    const float* Wl = lin_W + (size_t)l * HID * 256;
    {
        int k = tid, h = k >> 6, i = k & 63;
        const float* src = Wl + i * 256 + h * 64;
        float* dstp = wstack + (size_t)l * 256 * 64 + k * 64;
        for (int c = 0; c < 64; c += 4)
            *(float4*)(dstp + c) = *(const float4*)(src + c);
    }
    for (int idx = tid; idx < 512; idx += 256) {
        int v = idx >> 6, i = idx & 63;
        int h = v & 3;
        const float* av = (v < 4 ? att_src : att_dst) + (size_t)l * 256 + h * 64;
        const float* wr = Wl + i * 256 + h * 64;
        float p = 0.f;
        for (int c = 0; c < 64; ++c) p = fmaf(wr[c], av[c], p);
        watt[(size_t)l * 512 + v * 64 + i] = p;
    }
}

// ---------------- layer-0 GEMM (fp32, verified): h = elu(x @ Wi + bi) + fused layer-0 alpha ----

__global__ __launch_bounds__(256) void k_gemm_in(const float* __restrict__ x,
                                                 const float* __restrict__ Wi,
                                                 const float* __restrict__ bi,
                                                 const float* __restrict__ watt,  // [8][64]
                                                 float* __restrict__ h,
                                                 unsigned short* __restrict__ h_bf,
                                                 float* __restrict__ alpha_s,
                                                 float* __restrict__ alpha_d,
                                                 unsigned* __restrict__ mxk) {
    __shared__ float xT[IN_CH * 64];
    __shared__ float Ws[IN_CH * HID];
    __shared__ float wl[512];
    __shared__ unsigned s_mx[4];
    int tid = threadIdx.x;
    int row0 = blockIdx.x * 64;
    if (tid < 4) s_mx[tid] = 0;
    for (int i = tid; i < 512; i += 256) wl[i] = watt[i];
    for (int i = tid * 4; i < IN_CH * HID; i += 1024)
        *(float4*)(Ws + i) = *(const float4*)(Wi + i);
    {
        int r = tid >> 2, k0 = (tid & 3) * 32;
        int rr = row0 + r;
#pragma unroll
        for (int j = 0; j < 32; j += 4) {
            float4 v = (rr < N_NODES) ? *(const float4*)(x + (size_t)rr * IN_CH + k0 + j)
                                      : make_float4(0.f, 0.f, 0.f, 0.f);
            xT[(k0 + j    ) * 64 + r] = v.x;
            xT[(k0 + j + 1) * 64 + r] = v.y;
            xT[(k0 + j + 2) * 64 + r] = v.z;
            xT[(k0 + j + 3) * 64 + r] = v.w;
        }
    }
    __syncthreads();
    int tx = tid & 15, ty = tid >> 4;
    int c0 = tx * 4, r0 = ty * 4;
    float acc[4][4] = {};
    for (int k = 0; k < IN_CH; ++k) {
        float4 xv = *(const float4*)(xT + k * 64 + r0);
        float4 wv = *(const float4*)(Ws + k * HID + c0);
        float xr[4] = {xv.x, xv.y, xv.z, xv.w};
        float wc[4] = {wv.x, wv.y, wv.z, wv.w};
#pragma unroll
        for (int r = 0; r < 4; ++r)
#pragma unroll
            for (int c = 0; c < 4; ++c)
                acc[r][c] = fmaf(xr[r], wc[c], acc[r][c]);
    }
    float4 bv = *(const float4*)(bi + c0);
    float bcs[4] = {bv.x, bv.y, bv.z, bv.w};
    float rpmax[4] = {-1e30f, -1e30f, -1e30f, -1e30f};
#pragma unroll
    for (int r = 0; r < 4; ++r) {
        int rr = row0 + r0 + r;
        float vv[4];
#pragma unroll
        for (int c = 0; c < 4; ++c) {
            float t = acc[r][c] + bcs[c];
            vv[c] = t > 0.f ? t : (__expf(t) - 1.f);
        }
        if (rr < N_NODES) {
            *(float4*)(h + (size_t)rr * HID + c0) = make_float4(vv[0], vv[1], vv[2], vv[3]);
            unsigned short t4[4] = {f2bf(vv[0]), f2bf(vv[1]), f2bf(vv[2]), f2bf(vv[3])};
            *(uint2*)(h_bf + (size_t)rr * HID + c0) = *(uint2*)t4;
        }
        float red[8];
#pragma unroll
        for (int v = 0; v < 8; ++v) {
            const float* wv = wl + v * 64 + c0;
            float p = vv[0]*wv[0] + vv[1]*wv[1] + vv[2]*wv[2] + vv[3]*wv[3];
            p += __shfl_xor(p, 1, 64);
            p += __shfl_xor(p, 2, 64);
            p += __shfl_xor(p, 4, 64);
            p += __shfl_xor(p, 8, 64);
            red[v] = p;
        }
        if (tx == 0 && rr < N_NODES) {
            *(float4*)(alpha_s + (size_t)rr * 4) = make_float4(red[0], red[1], red[2], red[3]);
            *(float4*)(alpha_d + (size_t)rr * 4) = make_float4(red[4], red[5], red[6], red[7]);
#pragma unroll
            for (int hh = 0; hh < 4; ++hh) rpmax[hh] = fmaxf(rpmax[hh], red[hh]);
        }
    }
    if (tx == 0) {
#pragma unroll
        for (int hh = 0; hh < 4; ++hh) atomicMax(&s_mx[hh], fenc(rpmax[hh]));
    }
    __syncthreads();
    if (tid < 4) atomicMax(&mxk[tid], s_mx[tid]);
}

// ---------------- fused layer: aggregate (into LDS) + GEMV post + LN/ELU/residual + next alpha ----
// Phase 1: 8 lanes/node, depth-1 software-pipelined gathers (R15/R18-proven; depth-2,
// degree-permutation, and persistent-block variants all measured as regressions).
// Phase 2 = R13 k_post (32-row tile, 2x4 thread tile, W fp32 LDS chunks).

__global__ __launch_bounds__(256) void k_layer(
    const unsigned short* __restrict__ h_bf,    // [N][64] bf16 (current layer)
    const float* __restrict__ alpha_s,          // current
    const float* __restrict__ alpha_d,          // current
    const int* __restrict__ row_ptr,
    const int* __restrict__ csr_src,
    const unsigned* __restrict__ mxk,           // current [4]
    const float* __restrict__ wstack,           // [256][64] fp32
    const float* __restrict__ gat_b,
    const float* __restrict__ ln_g,
    const float* __restrict__ ln_b,
    const float* __restrict__ h_res,            // fp32 h (current layer input)
    const float* __restrict__ watt_next,        // [8][64]
    float* __restrict__ h_out,                  // fp32 next
    unsigned short* __restrict__ hbf_out,       // bf16 next (other buffer!)
    float* __restrict__ alpha_s_nxt,
    float* __restrict__ alpha_d_nxt,
    unsigned* __restrict__ mxk_next,
    int use_res, int do_alpha)
{
    __shared__ unsigned short aS[32 * AG_STRIDE];   // 16768 B
    __shared__ float Wc[32 * WC_STRIDE];            // 8704 B
    __shared__ unsigned s_mx[4];
    int tid = threadIdx.x;
    int row0 = blockIdx.x * 32;
    if (tid < 4) s_mx[tid] = 0;

    // -------- phase 1: aggregate this block's 32 nodes into aS (pipelined gathers) --------
    {
        int dl = tid >> 3, q = tid & 7;
        int d = row0 + dl;
        unsigned short* arow = aS + dl * AG_STRIDE + (q << 3);
        if (d < N_NODES) {
            int start = row_ptr[d], end = row_ptr[d + 1];
            float4 ad = *(const float4*)(alpha_d + (size_t)d * 4);
            float mp0 = lrelu(fdec(mxk[0]) + ad.x);
            float mp1 = lrelu(fdec(mxk[1]) + ad.y);
            float mp2 = lrelu(fdec(mxk[2]) + ad.z);
            float mp3 = lrelu(fdec(mxk[3]) + ad.w);

            float acc[4][8] = {};
            float ds0 = 0.f, ds1 = 0.f, ds2 = 0.f, ds3 = 0.f;

            // prologue: load edge `start`'s data
            int s = csr_src[start];
            float4 as = *(const float4*)(alpha_s + (size_t)s * 4);
            uint4  u  = *(const uint4*)(h_bf + ((size_t)s << 6) + (q << 3));

            for (int e = start; e < end; ++e) {
                // prefetch edge e+1 (clamped index; values unused at tail)
                int sn = (e + 1 < end) ? csr_src[e + 1] : 0;
                float4 as_n = *(const float4*)(alpha_s + (size_t)sn * 4);
                uint4  u_n  = *(const uint4*)(h_bf + ((size_t)sn << 6) + (q << 3));

                // compute edge e from registers loaded last iteration
                float w0 = __expf(lrelu(as.x + ad.x) - mp0);
                float w1 = __expf(lrelu(as.y + ad.y) - mp1);
                float w2 = __expf(lrelu(as.z + ad.z) - mp2);
                float w3 = __expf(lrelu(as.w + ad.w) - mp3);
                ds0 += w0; ds1 += w1; ds2 += w2; ds3 += w3;
                float f0 = bf_lo(u.x), f1 = bf_hi(u.x), f2 = bf_lo(u.y), f3 = bf_hi(u.y);
                float f4 = bf_lo(u.z), f5 = bf_hi(u.z), f6 = bf_lo(u.w), f7 = bf_hi(u.w);
                acc[0][0] = fmaf(w0, f0, acc[0][0]); acc[0][1] = fmaf(w0, f1, acc[0][1]);
                acc[0][2] = fmaf(w0, f2, acc[0][2]); acc[0][3] = fmaf(w0, f3, acc[0][3]);
                acc[0][4] = fmaf(w0, f4, acc[0][4]); acc[0][5] = fmaf(w0, f5, acc[0][5]);
                acc[0][6] = fmaf(w0, f6, acc[0][6]); acc[0][7] = fmaf(w0, f7, acc[0][7]);
                acc[1][0] = fmaf(w1, f0, acc[1][0]); acc[1][1] = fmaf(w1, f1, acc[1][1]);
                acc[1][2] = fmaf(w1, f2, acc[1][2]); acc[1][3] = fmaf(w1, f3, acc[1][3]);
                acc[1][4] = fmaf(w1, f4, acc[1][4]); acc[1][5] = fmaf(w1, f5, acc[1][5]);
                acc[1][6] = fmaf(w1, f6, acc[1][6]); acc[1][7] = fmaf(w1, f7, acc[1][7]);
                acc[2][0] = fmaf(w2, f0, acc[2][0]); acc[2][1] = fmaf(w2, f1, acc[2][1]);
                acc[2][2] = fmaf(w2, f2, acc[2][2]); acc[2][3] = fmaf(w2, f3, acc[2][3]);
                acc[2][4] = fmaf(w2, f4, acc[2][4]); acc[2][5] = fmaf(w2, f5, acc[2][5]);
                acc[2][6] = fmaf(w2, f6, acc[2][6]); acc[2][7] = fmaf(w2, f7, acc[2][7]);
                acc[3][0] = fmaf(w3, f0, acc[3][0]); acc[3][1] = fmaf(w3, f1, acc[3][1]);
                acc[3][2] = fmaf(w3, f2, acc[3][2]); acc[3][3] = fmaf(w3, f3, acc[3][3]);
                acc[3][4] = fmaf(w3, f4, acc[3][4]); acc[3][5] = fmaf(w3, f5, acc[3][5]);
                acc[3][6] = fmaf(w3, f6, acc[3][6]); acc[3][7] = fmaf(w3, f7, acc[3][7]);

                as = as_n; u = u_n; s = sn;
            }

            float inv[4] = {1.f / (ds0 + 1e-16f), 1.f / (ds1 + 1e-16f),
                            1.f / (ds2 + 1e-16f), 1.f / (ds3 + 1e-16f)};
#pragma unroll
            for (int hh = 0; hh < 4; ++hh) {
                unsigned short t8[8];
#pragma unroll
                for (int k = 0; k < 8; ++k) t8[k] = f2bf(acc[hh][k] * inv[hh]);
                *(uint4*)(arow + hh * 64) = *(uint4*)t8;
            }
        } else {
            uint4 z = make_uint4(0, 0, 0, 0);
#pragma unroll
            for (int hh = 0; hh < 4; ++hh) *(uint4*)(arow + hh * 64) = z;
        }
    }

    // -------- phase 2: y = aS @ W * 0.25 + bias; LN; ELU; residual; next alpha --------
    int tx = tid & 15, ty = tid >> 4;
    int c0 = tx * 4, r0 = ty * 2;
    float acc[2][4] = {};

    int wk = tid >> 3;            // 0..31 : k-row within chunk this thread stages
    int wc8 = (tid & 7) * 8;      // 8-col group
    for (int chunk = 0; chunk < 8; ++chunk) {
        __syncthreads();   // first iteration: covers aS readiness; later: Wc reader/writer fence
        {
            const float* wsrc = wstack + (size_t)(chunk * 32 + wk) * 64 + wc8;
            float* wdst = Wc + wk * WC_STRIDE + wc8;
            *(float4*)(wdst)     = *(const float4*)(wsrc);
            *(float4*)(wdst + 4) = *(const float4*)(wsrc + 4);
        }
        __syncthreads();
        int kbase = chunk * 32;
#pragma unroll
        for (int kb = 0; kb < 8; ++kb) {
            int kl = kb * 4;
            float4 w0 = *(const float4*)(Wc + (kl + 0) * WC_STRIDE + c0);
            float4 w1 = *(const float4*)(Wc + (kl + 1) * WC_STRIDE + c0);
            float4 w2 = *(const float4*)(Wc + (kl + 2) * WC_STRIDE + c0);
            float4 w3 = *(const float4*)(Wc + (kl + 3) * WC_STRIDE + c0);
#pragma unroll
            for (int r = 0; r < 2; ++r) {
                uint2 au = *(const uint2*)(aS + (r0 + r) * AG_STRIDE + kbase + kl);
                float a0 = bf_lo(au.x), a1 = bf_hi(au.x), a2 = bf_lo(au.y), a3 = bf_hi(au.y);
                acc[r][0] = fmaf(a0, w0.x, fmaf(a1, w1.x, fmaf(a2, w2.x, fmaf(a3, w3.x, acc[r][0]))));
                acc[r][1] = fmaf(a0, w0.y, fmaf(a1, w1.y, fmaf(a2, w2.y, fmaf(a3, w3.y, acc[r][1]))));
                acc[r][2] = fmaf(a0, w0.z, fmaf(a1, w1.z, fmaf(a2, w2.z, fmaf(a3, w3.z, acc[r][2]))));
                acc[r][3] = fmaf(a0, w0.w, fmaf(a1, w1.w, fmaf(a2, w2.w, fmaf(a3, w3.w, acc[r][3]))));
            }
        }
    }

    float4 gb = *(const float4*)(gat_b + c0);
    float bias[4] = {gb.x, gb.y, gb.z, gb.w};
    float4 lg = *(const float4*)(ln_g + c0);
    float4 lb = *(const float4*)(ln_b + c0);
    float gg[4] = {lg.x, lg.y, lg.z, lg.w};
    float bb[4] = {lb.x, lb.y, lb.z, lb.w};
    float rpmax[4] = {-1e30f, -1e30f, -1e30f, -1e30f};
#pragma unroll
    for (int r = 0; r < 2; ++r) {
        int rr = row0 + r0 + r;
        float o[4];
#pragma unroll
        for (int c = 0; c < 4; ++c) o[c] = acc[r][c] * 0.25f + bias[c];
        float s = o[0] + o[1] + o[2] + o[3];
        float s2 = o[0]*o[0] + o[1]*o[1] + o[2]*o[2] + o[3]*o[3];
        for (int off = 1; off < 16; off <<= 1) {
            s  += __shfl_xor(s,  off, 64);
            s2 += __shfl_xor(s2, off, 64);
        }
        float mu = s * (1.f / 64.f);
        float var = s2 * (1.f / 64.f) - mu * mu;
        float rstd = rsqrtf(var + LN_EPS);
        float vv[4];
#pragma unroll
        for (int c = 0; c < 4; ++c) {
            float t = (o[c] - mu) * rstd * gg[c] + bb[c];
            vv[c] = t > 0.f ? t : (__expf(t) - 1.f);
        }
        if (rr < N_NODES) {
            if (use_res) {
                float4 rv = *(const float4*)(h_res + (size_t)rr * HID + c0);
                vv[0] += rv.x; vv[1] += rv.y; vv[2] += rv.z; vv[3] += rv.w;
            }
            *(float4*)(h_out + (size_t)rr * HID + c0) = make_float4(vv[0], vv[1], vv[2], vv[3]);
            unsigned short t4[4] = {f2bf(vv[0]), f2bf(vv[1]), f2bf(vv[2]), f2bf(vv[3])};
            *(uint2*)(hbf_out + (size_t)rr * HID + c0) = *(uint2*)t4;
        }
        if (do_alpha) {
            float red[8];
#pragma unroll
            for (int v = 0; v < 8; ++v) {
                const float* wv = watt_next + v * 64 + c0;
                float p = vv[0]*wv[0] + vv[1]*wv[1] + vv[2]*wv[2] + vv[3]*wv[3];
                p += __shfl_xor(p, 1, 64);
                p += __shfl_xor(p, 2, 64);
                p += __shfl_xor(p, 4, 64);
                p += __shfl_xor(p, 8, 64);
                red[v] = p;
            }
            if (tx == 0 && rr < N_NODES) {
                *(float4*)(alpha_s_nxt + (size_t)rr * 4) = make_float4(red[0], red[1], red[2], red[3]);
                *(float4*)(alpha_d_nxt + (size_t)rr * 4) = make_float4(red[4], red[5], red[6], red[7]);
#pragma unroll
                for (int hh = 0; hh < 4; ++hh) rpmax[hh] = fmaxf(rpmax[hh], red[hh]);
            }
        }
    }
    if (do_alpha) {
        if (tx == 0) {
#pragma unroll
            for (int hh = 0; hh < 4; ++hh) atomicMax(&s_mx[hh], fenc(rpmax[hh]));
        }
        __syncthreads();
        if (tid < 4) atomicMax(&mxk_next[tid], s_mx[tid]);
    }
}

// ---------------- final GEMM (fp32, verified): out = h @ Wo + bo ----------------

__global__ __launch_bounds__(256) void k_gemm_out(const float* __restrict__ h,
                                                  const float* __restrict__ Wo,
                                                  const float* __restrict__ bo,
                                                  float* __restrict__ out) {
    __shared__ float Ws[HID * OUT_CH];
    __shared__ float hs[6 * HID];
    int tid = threadIdx.x;
    int row0 = blockIdx.x * 6;
    for (int i = tid; i < HID * OUT_CH; i += 256) Ws[i] = Wo[i];
    for (int i = tid; i < 6 * HID; i += 256) {
        int r = row0 + (i >> 6);
        hs[i] = (r < N_NODES) ? h[(size_t)r * HID + (i & 63)] : 0.f;
    }
    __syncthreads();
    if (tid < 240) {
        int r = tid / 40, o = tid - r * 40;
        int rr = row0 + r;
        if (rr < N_NODES) {
            float acc = bo[o];
            for (int k = 0; k < HID; ++k)
                acc = fmaf(hs[r * HID + k], Ws[k * OUT_CH + o], acc);
            out[(size_t)row0 * OUT_CH + tid] = acc;
        }
    }
}

// ---------------- launch ----------------

extern "C" void kernel_launch(void* const* d_in, const int* in_sizes, int n_in,
                              void* d_out, int out_size, void* d_ws, size_t ws_size,
                              hipStream_t stream) {
    const float* x       = (const float*)d_in[0];
    const int*   ei      = (const int*)  d_in[1];
    const float* Wi      = (const float*)d_in[2];
    const float* bi      = (const float*)d_in[3];
    const float* lin_W   = (const float*)d_in[4];
    const float* att_src = (const float*)d_in[5];
    const float* att_dst = (const float*)d_in[6];
    const float* gat_b   = (const float*)d_in[7];
    const float* ln_g    = (const float*)d_in[8];
    const float* ln_b    = (const float*)d_in[9];
    const float* Wo      = (const float*)d_in[10];
    const float* bo      = (const float*)d_in[11];
    float* out = (float*)d_out;

    char* ws = (char*)d_ws;
    size_t off = 0;
    auto alloc = [&](size_t bytes) -> void* {
        void* p = ws + off;
        off += (bytes + 255) & ~(size_t)255;
        return p;
    };
    float*          h_a      = (float*)alloc((size_t)N_NODES * HID * 4);
    float*          h_b      = (float*)alloc((size_t)N_NODES * HID * 4);
    unsigned short* hbf_a    = (unsigned short*)alloc((size_t)N_NODES * HID * 2);
    unsigned short* hbf_b    = (unsigned short*)alloc((size_t)N_NODES * HID * 2);
    float*          als_a    = (float*)alloc((size_t)N_NODES * 4 * 4);
    float*          ald_a    = (float*)alloc((size_t)N_NODES * 4 * 4);
    float*          als_b    = (float*)alloc((size_t)N_NODES * 4 * 4);
    float*          ald_b    = (float*)alloc((size_t)N_NODES * 4 * 4);
    int*            cnt      = (int*)  alloc((size_t)N_NODES * 4);
    int*            row_ptr  = (int*)  alloc((size_t)(N_NODES + 1) * 4);
    int*            csr_src  = (int*)  alloc((size_t)E_TOT * 4);
    int*            rank     = (int*)  alloc((size_t)E_TOT * 4);
    unsigned*       maxkey   = (unsigned*)alloc((size_t)LAYERS * 4 * 4);
    int*            bsum     = (int*)  alloc((size_t)SCAN_BLOCKS * 4);
    int*            boff     = (int*)  alloc((size_t)SCAN_BLOCKS * 4);
    float*          watt     = (float*)alloc((size_t)LAYERS * 8 * 64 * 4);
    float*          wstack   = (float*)alloc((size_t)LAYERS * 256 * 64 * 4);

    hipMemsetAsync(cnt, 0, (size_t)N_NODES * 4, stream);
    hipMemsetAsync(maxkey, 0, (size_t)LAYERS * 4 * 4, stream);

    int egrid = (E_TOT + 255) / 256;
    k_hist<<<egrid, 256, 0, stream>>>(ei, cnt, rank);
    k_scan_a<<<SCAN_BLOCKS, 1024, 0, stream>>>(cnt, row_ptr, bsum);
    k_scan_b<<<1, 64, 0, stream>>>(bsum, boff, row_ptr);
    k_scan_c<<<(N_NODES + 255) / 256, 256, 0, stream>>>(row_ptr, boff);
    k_scatter<<<egrid, 256, 0, stream>>>(ei, row_ptr, rank, csr_src);

    k_prep<<<LAYERS, 256, 0, stream>>>(lin_W, att_src, att_dst, watt, wstack);

    int rtiles = (N_NODES + 63) / 64;     // 782
    k_gemm_in<<<rtiles, 256, 0, stream>>>(x, Wi, bi, watt, h_a, hbf_a,
                                          als_a, ald_a, maxkey);

    int lgrid = (N_NODES + 31) / 32;      // 1563
    float*          h_cur   = h_a;   float*          h_nxt   = h_b;
    unsigned short* hbf_cur = hbf_a; unsigned short* hbf_nxt = hbf_b;
    float* als_cur = als_a; float* ald_cur = ald_a;
    float* als_nxt = als_b; float* ald_nxt = ald_b;
    for (int l = 0; l < LAYERS; ++l) {
        int do_alpha = (l + 1 < LAYERS) ? 1 : 0;
        k_layer<<<lgrid, 256, 0, stream>>>(hbf_cur, als_cur, ald_cur, row_ptr, csr_src,
                                           maxkey + l * 4,
                                           wstack + (size_t)l * 256 * 64,
                                           gat_b + (size_t)l * HID,
                                           ln_g + (size_t)l * HID,
                                           ln_b + (size_t)l * HID,
                                           h_cur,
                                           watt + (size_t)((l + 1) % LAYERS) * 512,
                                           h_nxt, hbf_nxt,
                                           als_nxt, ald_nxt,
                                           maxkey + (size_t)((l + 1) % LAYERS) * 4,
                                           l > 0 ? 1 : 0, do_alpha);
        { float* t = h_cur; h_cur = h_nxt; h_nxt = t; }
        { unsigned short* t = hbf_cur; hbf_cur = hbf_nxt; hbf_nxt = t; }
        { float* t = als_cur; als_cur = als_nxt; als_nxt = t; }
        { float* t = ald_cur; ald_cur = ald_nxt; ald_nxt = t; }
    }

    int ogrid = (N_NODES + 5) / 6;
    k_gemm_out<<<ogrid, 256, 0, stream>>>(h_cur, Wo, bo, out);
}